// Round 17
// baseline (7812.378 us; speedup 1.0000x reference)
//
#include <hip/hip_runtime.h>
#include <stdint.h>

#define BATCH   4
#define NPTS    16384
#define NPOINT  1024
#define KNN     20
#define KSEL    21   // K+1, includes self

typedef unsigned long long u64;

// ---------------------------------------------------------------------------
// FUSED single-dispatch (r17 = r16 + interference reduction):
//   blocks 0..3      : FPS (exact r8 codegen, fastest measured) publishing
//                      tagged u64 winners to slots[it*4+b]. s_setprio(3).
//   blocks 4..515    : knn_mid consumers (1 wave/query). s_setprio(0) +
//                      pre-sleep ~qi*2.2us before first poll.
//   blocks 516..1027 : knn_out consumers (1 wave/query), same staggering.
// r16 measured fps-in-fused 2560us vs 2311us standalone: ~250us of consumer
// interference (shared-CU issue slots + L1/L2 traffic). Priority + pre-sleep
// removes most of it. Slot protocol/tags/poison/replay semantics and ALL FP
// expression trees byte-identical to the validated r16 kernel.
// ---------------------------------------------------------------------------
#define FPS_THREADS 512
#define PPT (NPTS / FPS_THREADS)     // 32 points per thread, strided
#define KNN_MID_BLK0 4
#define KNN_OUT_BLK0 (4 + 512)
#define GRID_BLOCKS  (4 + 512 + 512)

__device__ __forceinline__ float opaque_f(float x) {
  __asm__ volatile("" : "+v"(x));
  return x;
}

// sleep ~qi * 2.2us (s_sleep(127) ~= 8128 clk ~= 3.4us @2.4GHz nominal;
// at the observed effective rate each unit covers ~1.5-3 fps iterations).
__device__ __forceinline__ void stagger_sleep(int qi) {
  int units = qi >> 1;   // ~0.5 unit per iteration index
  for (int s = 0; s < units; ++s) __builtin_amdgcn_s_sleep(127);
}

#define REPEAT32(M) \
  M(0) M(1) M(2) M(3) M(4) M(5) M(6) M(7) \
  M(8) M(9) M(10) M(11) M(12) M(13) M(14) M(15) \
  M(16) M(17) M(18) M(19) M(20) M(21) M(22) M(23) \
  M(24) M(25) M(26) M(27) M(28) M(29) M(30) M(31)

#define FPS_DECL(i) float px##i, py##i, pz##i, md##i;

#define FPS_INIT(i) { \
    int idx = (i) * FPS_THREADS + t; \
    px##i = opaque_f(P[idx * 3 + 0]); \
    py##i = opaque_f(P[idx * 3 + 1]); \
    pz##i = opaque_f(P[idx * 3 + 2]); \
    md##i = 1e10f; }

#define FPS_STEP(i) { \
    float dx = __fsub_rn(px##i, qx); \
    float dy = __fsub_rn(py##i, qy); \
    float dz = __fsub_rn(pz##i, qz); \
    float d  = __fadd_rn(__fadd_rn(__fmul_rn(dx, dx), __fmul_rn(dy, dy)), \
                         __fmul_rn(dz, dz)); \
    float m = fminf(md##i, d); \
    md##i = m; \
    bool g = (m > best); \
    best = g ? m : best; \
    bi   = g ? (i) : bi; }

__global__ __launch_bounds__(FPS_THREADS)
__attribute__((amdgpu_waves_per_eu(2, 2)))
void fused_kernel(const float* __restrict__ pts, float* __restrict__ out,
                  u64* __restrict__ slots,
                  float* __restrict__ out_nbr_mid,
                  float* __restrict__ out_d_mid,
                  float* __restrict__ out_nbr_out,
                  float* __restrict__ out_d_out) {
  if (blockIdx.x < 4) {
    // ================= FPS role: exact r8 body + slot publish =============
    __builtin_amdgcn_s_setprio(3);       // favor the latency-critical waves
    const int b = blockIdx.x;
    const float* P = pts + (size_t)b * NPTS * 3;
    float* out_ind = out;                   // [B,NPOINT] (indices as float)
    float* out_q   = out + BATCH * NPOINT;  // [B,NPOINT,3]
    const int t = threadIdx.x;

    REPEAT32(FPS_DECL)
    REPEAT32(FPS_INIT)

    __shared__ float s_val[2][FPS_THREADS / 64];
    __shared__ int   s_idx[2][FPS_THREADS / 64];

    if (t == 0) {
      out_ind[b * NPOINT] = 0.0f;
      float ax = P[0], ay = P[1], az = P[2];
      size_t o0 = (size_t)(b * NPOINT) * 3;
      out_q[o0 + 0] = ax; out_q[o0 + 1] = ay; out_q[o0 + 2] = az;
    }
    float qx = P[0], qy = P[1], qz = P[2];

    for (int it = 1; it < NPOINT; ++it) {
      const int p = it & 1;
      float best = -1.0f;
      int bi = 0;
      REPEAT32(FPS_STEP)
      int bidx = bi * FPS_THREADS + t;

      // wave argmax reduce, tie -> lower global index
#pragma unroll
      for (int off = 32; off >= 1; off >>= 1) {
        float ov = __shfl_down(best, off);
        int   oi = __shfl_down(bidx, off);
        if (ov > best || (ov == best && oi < bidx)) { best = ov; bidx = oi; }
      }

      if ((t & 63) == 0) { s_val[p][t >> 6] = best; s_idx[p][t >> 6] = bidx; }
      __syncthreads();

      float bv = s_val[p][0];
      int   bx = s_idx[p][0];
#pragma unroll
      for (int w = 1; w < FPS_THREADS / 64; ++w) {
        float v = s_val[p][w];
        int   x = s_idx[p][w];
        if (v > bv || (v == bv && x < bx)) { bv = v; bx = x; }
      }

      qx = P[bx * 3 + 0];
      qy = P[bx * 3 + 1];
      qz = P[bx * 3 + 2];

      if (t == 0) {
        // publish winner for consumers: bit63=0, [29:20]=it, [13:0]=idx
        u64 pv = (u64)(unsigned)(bx | (it << 20));
        __hip_atomic_store(&slots[(size_t)it * BATCH + b], pv,
                           __ATOMIC_RELAXED, __HIP_MEMORY_SCOPE_AGENT);
        out_ind[b * NPOINT + it] = (float)bx;
        size_t o = (size_t)(b * NPOINT + it) * 3;
        out_q[o + 0] = qx; out_q[o + 1] = qy; out_q[o + 2] = qz;
      }
    }
  } else if (blockIdx.x < KNN_OUT_BLK0) {
    // ================= knn_mid role: one wave per query ===================
#pragma clang fp contract(off)
    __builtin_amdgcn_s_setprio(0);
    const int kb   = blockIdx.x - KNN_MID_BLK0;
    const int wid  = kb * 8 + (threadIdx.x >> 6);
    const int lane = threadIdx.x & 63;
    const int b    = wid >> 10;
    const int qi   = wid & (NPOINT - 1);
    const float* C = pts + (size_t)b * NPTS * 3;

    int widx = 0;
    if (qi > 0) {
      stagger_sleep(qi);                 // stay off the machine during fps
      const u64* sp = slots + (size_t)qi * BATCH + b;
      u64 v;
      for (;;) {
        v = __hip_atomic_load(sp, __ATOMIC_RELAXED,
                              __HIP_MEMORY_SCOPE_AGENT);
        if ((v >> 63) == 0 &&
            ((((unsigned)(v >> 20)) & 0x3FFu) == (unsigned)qi)) break;
        __builtin_amdgcn_s_sleep(64);
      }
      widx = (int)((unsigned)v & 0x3FFFu);
    }

    // q coords bit-identical to out_q (fps writes exactly P[widx])
    const float qx = C[widx * 3 + 0];
    const float qy = C[widx * 3 + 1];
    const float qz = C[widx * 3 + 2];
    const float qq = (qx * qx + qy * qy) + qz * qz;

    u64 best[KSEL];
#pragma unroll
    for (int j = 0; j < KSEL; ++j) best[j] = 0xFFFFFFFFFFFFFFFFull;

    for (int j = lane; j < NPTS; j += 64) {
      float px = C[j * 3 + 0], py = C[j * 3 + 1], pz = C[j * 3 + 2];
      float pp  = (px * px + py * py) + pz * pz;
      float dot = __builtin_fmaf(qz, pz, __builtin_fmaf(qy, py, qx * px));
      float d = (qq + pp) - 2.0f * dot;
      d = fmaxf(d, 0.0f);
      u64 key = ((u64)__float_as_uint(d) << 32) | (unsigned)j;
      if (key < best[KSEL - 1]) {
        u64 c = key;
#pragma unroll
        for (int s = 0; s < KSEL; ++s) {
          u64 o = best[s];
          bool l = c < o;
          u64 nb = l ? c : o;
          c = l ? o : c;
          best[s] = nb;
        }
      }
    }

    // LDS-free 64-way merge (validated r14/r16)
    int hp = 1;
    u64 head = best[0];
    int myK = -1, myIdx = 0;
#pragma unroll
    for (int r = 0; r < KSEL; ++r) {
      u64 v = head; int src = lane;
#pragma unroll
      for (int off = 32; off >= 1; off >>= 1) {
        u64 ov = __shfl_down(v, off);
        int os = __shfl_down(src, off);
        if (ov < v) { v = ov; src = os; }  // keys unique (idx embedded)
      }
      v   = __shfl(v, 0);
      src = __shfl(src, 0);
      if (r >= 1 && lane == r - 1) {       // drop r==0 (self)
        myIdx = (int)(unsigned)(v & 0xFFFFFFFFull);
        myK = r - 1;
      }
      if (lane == src) {
        u64 h = 0xFFFFFFFFFFFFFFFFull;
#pragma unroll
        for (int s = 1; s < KSEL; ++s) if (hp == s) h = best[s];
        head = h;
        hp++;
      }
    }

    if (myK >= 0) {
      size_t o = (size_t)(b * NPOINT + qi) * KNN + myK;
      out_nbr_mid[o] = (float)myIdx;
      float sx = C[myIdx * 3 + 0], sy = C[myIdx * 3 + 1],
            sz = C[myIdx * 3 + 2];
      out_d_mid[o * 3 + 0] = qx - sx;
      out_d_mid[o * 3 + 1] = qy - sy;
      out_d_mid[o * 3 + 2] = qz - sz;
    }
  } else {
    // ================= knn_out role: one wave per query ===================
#pragma clang fp contract(off)
    __builtin_amdgcn_s_setprio(0);
    const int kb   = blockIdx.x - KNN_OUT_BLK0;
    const int wid  = kb * 8 + (threadIdx.x >> 6);
    const int lane = threadIdx.x & 63;
    const int b    = wid >> 10;
    const int qi   = wid & (NPOINT - 1);
    const float* C = pts + (size_t)b * NPTS * 3;

    // needs ALL 1024 winners: sleep out most of fps first
    stagger_sleep(NPOINT - 2);

    // my query's point index
    int wq = 0;
    if (qi > 0) {
      const u64* sp = slots + (size_t)qi * BATCH + b;
      u64 v;
      for (;;) {
        v = __hip_atomic_load(sp, __ATOMIC_RELAXED,
                              __HIP_MEMORY_SCOPE_AGENT);
        if ((v >> 63) == 0 &&
            ((((unsigned)(v >> 20)) & 0x3FFu) == (unsigned)qi)) break;
        __builtin_amdgcn_s_sleep(64);
      }
      wq = (int)((unsigned)v & 0x3FFFu);
    }
    const float qx = C[wq * 3 + 0];
    const float qy = C[wq * 3 + 1];
    const float qz = C[wq * 3 + 2];
    const float qq = (qx * qx + qy * qy) + qz * qz;

    // candidate point indices for my 16 positions (self-tagged words:
    // no publish-order assumption)
    int wj[NPOINT / 64];
#pragma unroll
    for (int u = 0; u < NPOINT / 64; ++u) {
      int j = u * 64 + lane;
      int w = 0;
      if (j > 0) {
        const u64* sp = slots + (size_t)j * BATCH + b;
        u64 v;
        for (;;) {
          v = __hip_atomic_load(sp, __ATOMIC_RELAXED,
                                __HIP_MEMORY_SCOPE_AGENT);
          if ((v >> 63) == 0 &&
              ((((unsigned)(v >> 20)) & 0x3FFu) == (unsigned)j)) break;
          __builtin_amdgcn_s_sleep(64);
        }
        w = (int)((unsigned)v & 0x3FFFu);
      }
      wj[u] = w;
    }

    u64 best[KSEL];
#pragma unroll
    for (int j = 0; j < KSEL; ++j) best[j] = 0xFFFFFFFFFFFFFFFFull;

#pragma unroll
    for (int u = 0; u < NPOINT / 64; ++u) {
      int j = u * 64 + lane;               // candidate POSITION (the key idx)
      int w = wj[u];
      float px = C[w * 3 + 0], py = C[w * 3 + 1], pz = C[w * 3 + 2];
      float pp  = (px * px + py * py) + pz * pz;
      float dot = __builtin_fmaf(qz, pz, __builtin_fmaf(qy, py, qx * px));
      float d = (qq + pp) - 2.0f * dot;
      d = fmaxf(d, 0.0f);
      u64 key = ((u64)__float_as_uint(d) << 32) | (unsigned)j;
      if (key < best[KSEL - 1]) {
        u64 c = key;
#pragma unroll
        for (int s = 0; s < KSEL; ++s) {
          u64 o = best[s];
          bool l = c < o;
          u64 nb = l ? c : o;
          c = l ? o : c;
          best[s] = nb;
        }
      }
    }

    // LDS-free 64-way merge (validated r14/r16)
    int hp = 1;
    u64 head = best[0];
    int myK = -1, myIdx = 0;
#pragma unroll
    for (int r = 0; r < KSEL; ++r) {
      u64 v = head; int src = lane;
#pragma unroll
      for (int off = 32; off >= 1; off >>= 1) {
        u64 ov = __shfl_down(v, off);
        int os = __shfl_down(src, off);
        if (ov < v) { v = ov; src = os; }
      }
      v   = __shfl(v, 0);
      src = __shfl(src, 0);
      if (r >= 1 && lane == r - 1) {
        myIdx = (int)(unsigned)(v & 0xFFFFFFFFull);
        myK = r - 1;
      }
      if (lane == src) {
        u64 h = 0xFFFFFFFFFFFFFFFFull;
#pragma unroll
        for (int s = 1; s < KSEL; ++s) if (hp == s) h = best[s];
        head = h;
        hp++;
      }
    }

    if (myK >= 0) {
      size_t o = (size_t)(b * NPOINT + qi) * KNN + myK;
      out_nbr_out[o] = (float)myIdx;
      int w = 0;
      if (myIdx > 0) {
        u64 v = __hip_atomic_load(slots + (size_t)myIdx * BATCH + b,
                                  __ATOMIC_RELAXED, __HIP_MEMORY_SCOPE_AGENT);
        w = (int)((unsigned)v & 0x3FFFu);
      }
      float sx = C[w * 3 + 0], sy = C[w * 3 + 1], sz = C[w * 3 + 2];
      out_d_out[o * 3 + 0] = qx - sx;
      out_d_out[o * 3 + 1] = qy - sy;
      out_d_out[o * 3 + 2] = qz - sz;
    }
  }
}

// ---------------------------------------------------------------------------
extern "C" void kernel_launch(void* const* d_in, const int* in_sizes, int n_in,
                              void* d_out, int out_size, void* d_ws,
                              size_t ws_size, hipStream_t stream) {
  (void)in_sizes; (void)n_in; (void)out_size; (void)ws_size;
  const float* pts = (const float*)d_in[0];
  float* out = (float*)d_out;

  // ws layout: slots only — 1024 x 4 x 8B = 32 KB
  u64* slots = (u64*)d_ws;

  // output layout (floats): [xyz_ind | xyz_query | nbr_mid | d_mid | nbr_out | d_out]
  float* out_nbr_mid = out + (size_t)BATCH * NPOINT * 4;
  float* out_d_mid   = out_nbr_mid + (size_t)BATCH * NPOINT * KNN;
  float* out_nbr_out = out_d_mid + (size_t)BATCH * NPOINT * KNN * 3;
  float* out_d_out   = out_nbr_out + (size_t)BATCH * NPOINT * KNN;

  hipLaunchKernelGGL(fused_kernel, dim3(GRID_BLOCKS), dim3(FPS_THREADS), 0,
                     stream, pts, out, slots,
                     out_nbr_mid, out_d_mid, out_nbr_out, out_d_out);
}

// Round 18
// 2584.761 us; speedup vs baseline: 3.0225x; 3.0225x over previous
//
#include <hip/hip_runtime.h>
#include <stdint.h>

#define BATCH   4
#define NPTS    16384
#define NPOINT  1024
#define KNN     20
#define KSEL    21   // K+1, includes self

typedef unsigned long long u64;

// ---------------------------------------------------------------------------
// FUSED single-dispatch (r18 = exact r16 + s_setprio ONLY):
//   blocks 0..3      : FPS (exact r8 codegen) publishing tagged u64 winners
//                      to slots[it*4+b]. s_setprio(3).
//   blocks 4..515    : knn_mid consumers (1 wave/query). s_setprio(0).
//   blocks 516..1027 : knn_out consumers (1 wave/query). s_setprio(0).
// r17's stagger_sleep was miscalibrated (~8us/unit -> up to ~4ms oversleep,
// total 7.8ms). Removed. Poll loops keep short validated s_sleep backoff.
// Slot word: bit63=0, [29:20]=it tag, [13:0]=widx; 0xAA poison and zeroed ws
// read "unpublished"; deterministic -> replay idempotent. Consumers only
// poll, producer never waits -> deadlock-free. ALL FP expression trees
// byte-identical to the validated r16 kernel (absmax 0.0).
// ---------------------------------------------------------------------------
#define FPS_THREADS 512
#define PPT (NPTS / FPS_THREADS)     // 32 points per thread, strided
#define KNN_MID_BLK0 4
#define KNN_OUT_BLK0 (4 + 512)
#define GRID_BLOCKS  (4 + 512 + 512)

__device__ __forceinline__ float opaque_f(float x) {
  __asm__ volatile("" : "+v"(x));
  return x;
}

#define REPEAT32(M) \
  M(0) M(1) M(2) M(3) M(4) M(5) M(6) M(7) \
  M(8) M(9) M(10) M(11) M(12) M(13) M(14) M(15) \
  M(16) M(17) M(18) M(19) M(20) M(21) M(22) M(23) \
  M(24) M(25) M(26) M(27) M(28) M(29) M(30) M(31)

#define FPS_DECL(i) float px##i, py##i, pz##i, md##i;

#define FPS_INIT(i) { \
    int idx = (i) * FPS_THREADS + t; \
    px##i = opaque_f(P[idx * 3 + 0]); \
    py##i = opaque_f(P[idx * 3 + 1]); \
    pz##i = opaque_f(P[idx * 3 + 2]); \
    md##i = 1e10f; }

#define FPS_STEP(i) { \
    float dx = __fsub_rn(px##i, qx); \
    float dy = __fsub_rn(py##i, qy); \
    float dz = __fsub_rn(pz##i, qz); \
    float d  = __fadd_rn(__fadd_rn(__fmul_rn(dx, dx), __fmul_rn(dy, dy)), \
                         __fmul_rn(dz, dz)); \
    float m = fminf(md##i, d); \
    md##i = m; \
    bool g = (m > best); \
    best = g ? m : best; \
    bi   = g ? (i) : bi; }

__global__ __launch_bounds__(FPS_THREADS)
__attribute__((amdgpu_waves_per_eu(2, 2)))
void fused_kernel(const float* __restrict__ pts, float* __restrict__ out,
                  u64* __restrict__ slots,
                  float* __restrict__ out_nbr_mid,
                  float* __restrict__ out_d_mid,
                  float* __restrict__ out_nbr_out,
                  float* __restrict__ out_d_out) {
  if (blockIdx.x < 4) {
    // ================= FPS role: exact r8 body + slot publish =============
    __builtin_amdgcn_s_setprio(3);       // favor the latency-critical waves
    const int b = blockIdx.x;
    const float* P = pts + (size_t)b * NPTS * 3;
    float* out_ind = out;                   // [B,NPOINT] (indices as float)
    float* out_q   = out + BATCH * NPOINT;  // [B,NPOINT,3]
    const int t = threadIdx.x;

    REPEAT32(FPS_DECL)
    REPEAT32(FPS_INIT)

    __shared__ float s_val[2][FPS_THREADS / 64];
    __shared__ int   s_idx[2][FPS_THREADS / 64];

    if (t == 0) {
      out_ind[b * NPOINT] = 0.0f;
      float ax = P[0], ay = P[1], az = P[2];
      size_t o0 = (size_t)(b * NPOINT) * 3;
      out_q[o0 + 0] = ax; out_q[o0 + 1] = ay; out_q[o0 + 2] = az;
    }
    float qx = P[0], qy = P[1], qz = P[2];

    for (int it = 1; it < NPOINT; ++it) {
      const int p = it & 1;
      float best = -1.0f;
      int bi = 0;
      REPEAT32(FPS_STEP)
      int bidx = bi * FPS_THREADS + t;

      // wave argmax reduce, tie -> lower global index
#pragma unroll
      for (int off = 32; off >= 1; off >>= 1) {
        float ov = __shfl_down(best, off);
        int   oi = __shfl_down(bidx, off);
        if (ov > best || (ov == best && oi < bidx)) { best = ov; bidx = oi; }
      }

      if ((t & 63) == 0) { s_val[p][t >> 6] = best; s_idx[p][t >> 6] = bidx; }
      __syncthreads();

      float bv = s_val[p][0];
      int   bx = s_idx[p][0];
#pragma unroll
      for (int w = 1; w < FPS_THREADS / 64; ++w) {
        float v = s_val[p][w];
        int   x = s_idx[p][w];
        if (v > bv || (v == bv && x < bx)) { bv = v; bx = x; }
      }

      qx = P[bx * 3 + 0];
      qy = P[bx * 3 + 1];
      qz = P[bx * 3 + 2];

      if (t == 0) {
        // publish winner for consumers: bit63=0, [29:20]=it, [13:0]=idx
        u64 pv = (u64)(unsigned)(bx | (it << 20));
        __hip_atomic_store(&slots[(size_t)it * BATCH + b], pv,
                           __ATOMIC_RELAXED, __HIP_MEMORY_SCOPE_AGENT);
        out_ind[b * NPOINT + it] = (float)bx;
        size_t o = (size_t)(b * NPOINT + it) * 3;
        out_q[o + 0] = qx; out_q[o + 1] = qy; out_q[o + 2] = qz;
      }
    }
  } else if (blockIdx.x < KNN_OUT_BLK0) {
    // ================= knn_mid role: one wave per query ===================
#pragma clang fp contract(off)
    __builtin_amdgcn_s_setprio(0);
    const int kb   = blockIdx.x - KNN_MID_BLK0;
    const int wid  = kb * 8 + (threadIdx.x >> 6);
    const int lane = threadIdx.x & 63;
    const int b    = wid >> 10;
    const int qi   = wid & (NPOINT - 1);
    const float* C = pts + (size_t)b * NPTS * 3;

    int widx = 0;
    if (qi > 0) {
      const u64* sp = slots + (size_t)qi * BATCH + b;
      u64 v;
      for (;;) {
        v = __hip_atomic_load(sp, __ATOMIC_RELAXED,
                              __HIP_MEMORY_SCOPE_AGENT);
        if ((v >> 63) == 0 &&
            ((((unsigned)(v >> 20)) & 0x3FFu) == (unsigned)qi)) break;
        __builtin_amdgcn_s_sleep(32);
      }
      widx = (int)((unsigned)v & 0x3FFFu);
    }

    // q coords bit-identical to out_q (fps writes exactly P[widx])
    const float qx = C[widx * 3 + 0];
    const float qy = C[widx * 3 + 1];
    const float qz = C[widx * 3 + 2];
    const float qq = (qx * qx + qy * qy) + qz * qz;

    u64 best[KSEL];
#pragma unroll
    for (int j = 0; j < KSEL; ++j) best[j] = 0xFFFFFFFFFFFFFFFFull;

    for (int j = lane; j < NPTS; j += 64) {
      float px = C[j * 3 + 0], py = C[j * 3 + 1], pz = C[j * 3 + 2];
      float pp  = (px * px + py * py) + pz * pz;
      float dot = __builtin_fmaf(qz, pz, __builtin_fmaf(qy, py, qx * px));
      float d = (qq + pp) - 2.0f * dot;
      d = fmaxf(d, 0.0f);
      u64 key = ((u64)__float_as_uint(d) << 32) | (unsigned)j;
      if (key < best[KSEL - 1]) {
        u64 c = key;
#pragma unroll
        for (int s = 0; s < KSEL; ++s) {
          u64 o = best[s];
          bool l = c < o;
          u64 nb = l ? c : o;
          c = l ? o : c;
          best[s] = nb;
        }
      }
    }

    // LDS-free 64-way merge (validated r14/r16)
    int hp = 1;
    u64 head = best[0];
    int myK = -1, myIdx = 0;
#pragma unroll
    for (int r = 0; r < KSEL; ++r) {
      u64 v = head; int src = lane;
#pragma unroll
      for (int off = 32; off >= 1; off >>= 1) {
        u64 ov = __shfl_down(v, off);
        int os = __shfl_down(src, off);
        if (ov < v) { v = ov; src = os; }  // keys unique (idx embedded)
      }
      v   = __shfl(v, 0);
      src = __shfl(src, 0);
      if (r >= 1 && lane == r - 1) {       // drop r==0 (self)
        myIdx = (int)(unsigned)(v & 0xFFFFFFFFull);
        myK = r - 1;
      }
      if (lane == src) {
        u64 h = 0xFFFFFFFFFFFFFFFFull;
#pragma unroll
        for (int s = 1; s < KSEL; ++s) if (hp == s) h = best[s];
        head = h;
        hp++;
      }
    }

    if (myK >= 0) {
      size_t o = (size_t)(b * NPOINT + qi) * KNN + myK;
      out_nbr_mid[o] = (float)myIdx;
      float sx = C[myIdx * 3 + 0], sy = C[myIdx * 3 + 1],
            sz = C[myIdx * 3 + 2];
      out_d_mid[o * 3 + 0] = qx - sx;
      out_d_mid[o * 3 + 1] = qy - sy;
      out_d_mid[o * 3 + 2] = qz - sz;
    }
  } else {
    // ================= knn_out role: one wave per query ===================
#pragma clang fp contract(off)
    __builtin_amdgcn_s_setprio(0);
    const int kb   = blockIdx.x - KNN_OUT_BLK0;
    const int wid  = kb * 8 + (threadIdx.x >> 6);
    const int lane = threadIdx.x & 63;
    const int b    = wid >> 10;
    const int qi   = wid & (NPOINT - 1);
    const float* C = pts + (size_t)b * NPTS * 3;

    // my query's point index
    int wq = 0;
    if (qi > 0) {
      const u64* sp = slots + (size_t)qi * BATCH + b;
      u64 v;
      for (;;) {
        v = __hip_atomic_load(sp, __ATOMIC_RELAXED,
                              __HIP_MEMORY_SCOPE_AGENT);
        if ((v >> 63) == 0 &&
            ((((unsigned)(v >> 20)) & 0x3FFu) == (unsigned)qi)) break;
        __builtin_amdgcn_s_sleep(32);
      }
      wq = (int)((unsigned)v & 0x3FFFu);
    }
    const float qx = C[wq * 3 + 0];
    const float qy = C[wq * 3 + 1];
    const float qz = C[wq * 3 + 2];
    const float qq = (qx * qx + qy * qy) + qz * qz;

    // candidate point indices for my 16 positions (self-tagged words:
    // no publish-order assumption)
    int wj[NPOINT / 64];
#pragma unroll
    for (int u = 0; u < NPOINT / 64; ++u) {
      int j = u * 64 + lane;
      int w = 0;
      if (j > 0) {
        const u64* sp = slots + (size_t)j * BATCH + b;
        u64 v;
        for (;;) {
          v = __hip_atomic_load(sp, __ATOMIC_RELAXED,
                                __HIP_MEMORY_SCOPE_AGENT);
          if ((v >> 63) == 0 &&
              ((((unsigned)(v >> 20)) & 0x3FFu) == (unsigned)j)) break;
          __builtin_amdgcn_s_sleep(64);
        }
        w = (int)((unsigned)v & 0x3FFFu);
      }
      wj[u] = w;
    }

    u64 best[KSEL];
#pragma unroll
    for (int j = 0; j < KSEL; ++j) best[j] = 0xFFFFFFFFFFFFFFFFull;

#pragma unroll
    for (int u = 0; u < NPOINT / 64; ++u) {
      int j = u * 64 + lane;               // candidate POSITION (the key idx)
      int w = wj[u];
      float px = C[w * 3 + 0], py = C[w * 3 + 1], pz = C[w * 3 + 2];
      float pp  = (px * px + py * py) + pz * pz;
      float dot = __builtin_fmaf(qz, pz, __builtin_fmaf(qy, py, qx * px));
      float d = (qq + pp) - 2.0f * dot;
      d = fmaxf(d, 0.0f);
      u64 key = ((u64)__float_as_uint(d) << 32) | (unsigned)j;
      if (key < best[KSEL - 1]) {
        u64 c = key;
#pragma unroll
        for (int s = 0; s < KSEL; ++s) {
          u64 o = best[s];
          bool l = c < o;
          u64 nb = l ? c : o;
          c = l ? o : c;
          best[s] = nb;
        }
      }
    }

    // LDS-free 64-way merge (validated r14/r16)
    int hp = 1;
    u64 head = best[0];
    int myK = -1, myIdx = 0;
#pragma unroll
    for (int r = 0; r < KSEL; ++r) {
      u64 v = head; int src = lane;
#pragma unroll
      for (int off = 32; off >= 1; off >>= 1) {
        u64 ov = __shfl_down(v, off);
        int os = __shfl_down(src, off);
        if (ov < v) { v = ov; src = os; }
      }
      v   = __shfl(v, 0);
      src = __shfl(src, 0);
      if (r >= 1 && lane == r - 1) {
        myIdx = (int)(unsigned)(v & 0xFFFFFFFFull);
        myK = r - 1;
      }
      if (lane == src) {
        u64 h = 0xFFFFFFFFFFFFFFFFull;
#pragma unroll
        for (int s = 1; s < KSEL; ++s) if (hp == s) h = best[s];
        head = h;
        hp++;
      }
    }

    if (myK >= 0) {
      size_t o = (size_t)(b * NPOINT + qi) * KNN + myK;
      out_nbr_out[o] = (float)myIdx;
      int w = 0;
      if (myIdx > 0) {
        u64 v = __hip_atomic_load(slots + (size_t)myIdx * BATCH + b,
                                  __ATOMIC_RELAXED, __HIP_MEMORY_SCOPE_AGENT);
        w = (int)((unsigned)v & 0x3FFFu);
      }
      float sx = C[w * 3 + 0], sy = C[w * 3 + 1], sz = C[w * 3 + 2];
      out_d_out[o * 3 + 0] = qx - sx;
      out_d_out[o * 3 + 1] = qy - sy;
      out_d_out[o * 3 + 2] = qz - sz;
    }
  }
}

// ---------------------------------------------------------------------------
extern "C" void kernel_launch(void* const* d_in, const int* in_sizes, int n_in,
                              void* d_out, int out_size, void* d_ws,
                              size_t ws_size, hipStream_t stream) {
  (void)in_sizes; (void)n_in; (void)out_size; (void)ws_size;
  const float* pts = (const float*)d_in[0];
  float* out = (float*)d_out;

  // ws layout: slots only — 1024 x 4 x 8B = 32 KB
  u64* slots = (u64*)d_ws;

  // output layout (floats): [xyz_ind | xyz_query | nbr_mid | d_mid | nbr_out | d_out]
  float* out_nbr_mid = out + (size_t)BATCH * NPOINT * 4;
  float* out_d_mid   = out_nbr_mid + (size_t)BATCH * NPOINT * KNN;
  float* out_nbr_out = out_d_mid + (size_t)BATCH * NPOINT * KNN * 3;
  float* out_d_out   = out_nbr_out + (size_t)BATCH * NPOINT * KNN;

  hipLaunchKernelGGL(fused_kernel, dim3(GRID_BLOCKS), dim3(FPS_THREADS), 0,
                     stream, pts, out, slots,
                     out_nbr_mid, out_d_mid, out_nbr_out, out_d_out);
}